// Round 1
// baseline (1204.179 us; speedup 1.0000x reference)
//
#include <hip/hip_runtime.h>
#include <stdint.h>

// MoE: B=4096 tokens, D=1024, H=4096, O=1024, N=8 experts, top-5 Boltzmann gate (T=e).
// Strategy: bf16 MFMA GEMMs (m97 128x128 structure, global_load_lds width=16).
// FFN1 folds gate weight into H1s so FFN2 is a single K=N*H GEMM summed over experts.

#define B_TOK 4096
#define DD 1024
#define HH 4096
#define OO 1024
#define NE 8
#define NA_K 5

typedef __attribute__((ext_vector_type(8))) __bf16 bf16x8;
typedef __attribute__((ext_vector_type(4))) float f32x4;

__device__ __forceinline__ unsigned short f2bf(float f) {
  unsigned u = __float_as_uint(f);
  u += 0x7FFF + ((u >> 16) & 1);   // round-to-nearest-even
  return (unsigned short)(u >> 16);
}

__device__ __forceinline__ void gload_lds16(const void* g, void* l) {
  __builtin_amdgcn_global_load_lds(
      (const __attribute__((address_space(1))) void*)g,
      (__attribute__((address_space(3))) void*)l, 16, 0, 0);
}

// ---------------- fp32 -> bf16 convert ----------------
__global__ void moe_cvt_kernel(const float* __restrict__ src,
                               unsigned short* __restrict__ dst, int count4) {
  int i = blockIdx.x * blockDim.x + threadIdx.x;
  const int stride = gridDim.x * blockDim.x;
  for (; i < count4; i += stride) {
    const float4 v = ((const float4*)src)[i];
    ushort4 o;
    o.x = f2bf(v.x); o.y = f2bf(v.y); o.z = f2bf(v.z); o.w = f2bf(v.w);
    ((ushort4*)dst)[i] = o;
  }
}

// ---------------- gate: logits -> softmax/T -> top-5 -> renorm weights ----------------
__global__ __launch_bounds__(256) void moe_gate_kernel(
    const float* __restrict__ x, const float* __restrict__ Wg,
    const float* __restrict__ bg, float* __restrict__ gatew) {
  const int b = blockIdx.x;
  const int t = threadIdx.x;
  const float4 xv = ((const float4*)(x + (size_t)b * DD))[t];
  float part[NE];
#pragma unroll
  for (int n = 0; n < NE; ++n) {
    const float4 wv = ((const float4*)(Wg + (size_t)n * DD))[t];
    part[n] = xv.x * wv.x + xv.y * wv.y + xv.z * wv.z + xv.w * wv.w;
  }
#pragma unroll
  for (int n = 0; n < NE; ++n)
#pragma unroll
    for (int off = 32; off > 0; off >>= 1)
      part[n] += __shfl_down(part[n], off);
  __shared__ float red[4][NE];
  const int l = t & 63, w = t >> 6;
  if (l == 0) {
#pragma unroll
    for (int n = 0; n < NE; ++n) red[w][n] = part[n];
  }
  __syncthreads();
  if (t == 0) {
    float lg[NE];
#pragma unroll
    for (int n = 0; n < NE; ++n)
      lg[n] = red[0][n] + red[1][n] + red[2][n] + red[3][n] + bg[n];
    float mx = lg[0];
#pragma unroll
    for (int n = 1; n < NE; ++n) mx = fmaxf(mx, lg[n]);
    const float invT = 0.36787944117144233f;  // 1/e
    float p[NE], s = 0.0f;
#pragma unroll
    for (int n = 0; n < NE; ++n) { p[n] = expf((lg[n] - mx) * invT); s += p[n]; }
#pragma unroll
    for (int n = 0; n < NE; ++n) p[n] /= s;
    bool sel[NE];
#pragma unroll
    for (int n = 0; n < NE; ++n) sel[n] = false;
    float ssum = 0.0f;
    for (int k2 = 0; k2 < NA_K; ++k2) {   // stable argmax: lowest index wins ties (lax.top_k)
      int best = -1; float bv = -1e30f;
      for (int n = 0; n < NE; ++n)
        if (!sel[n] && p[n] > bv) { bv = p[n]; best = n; }
      sel[best] = true; ssum += p[best];
    }
    const float inv = 1.0f / (ssum + 1e-8f);
#pragma unroll
    for (int n = 0; n < NE; ++n)
      gatew[(size_t)b * NE + n] = sel[n] ? p[n] * inv : 0.0f;
  }
}

// ---------------- FFN1: H1s[n,b,h] = relu(x@W1[n]^T + b1[n]) * w[b,n]  (bf16) ----------------
__global__ __launch_bounds__(256, 2) void moe_ffn1_kernel(
    const unsigned short* __restrict__ xbf,   // [B,D]
    const unsigned short* __restrict__ W1bf,  // [N,H,D]
    const float* __restrict__ b1,             // [N,H]
    const float* __restrict__ gatew,          // [B,N]
    unsigned short* __restrict__ H1s) {       // [N,B,H]
  const int n  = blockIdx.z;
  const int tm = blockIdx.y * 128;  // token base
  const int tn = blockIdx.x * 128;  // h base
  const int t  = threadIdx.x;
  const int l  = t & 63;
  const int w  = t >> 6;
  const int wr = w >> 1, wc = w & 1;
  const int lrow = l & 15, lk = l >> 4;

  __shared__ __align__(16) unsigned short lds_a[128 * 32];
  __shared__ __align__(16) unsigned short lds_b[128 * 32];

  const unsigned short* Abase = xbf + (size_t)tm * DD;
  const unsigned short* Bbase = W1bf + ((size_t)n * HH + tn) * DD;

  f32x4 acc[4][4] = {};

  char* la = (char*)lds_a + w * 1024;
  char* lb = (char*)lds_b + w * 1024;
  const int r0 = t >> 2;          // tile row for staging
  const int cb = (t & 3) * 8;     // tile col (elems)

  for (int kk = 0; kk < DD / 32; ++kk) {
    const unsigned short* Ak = Abase + kk * 32 + cb;
    const unsigned short* Bk = Bbase + kk * 32 + cb;
    gload_lds16(Ak + (size_t)r0 * DD, la);
    gload_lds16(Ak + (size_t)(r0 + 64) * DD, la + 4096);
    gload_lds16(Bk + (size_t)r0 * DD, lb);
    gload_lds16(Bk + (size_t)(r0 + 64) * DD, lb + 4096);
    __syncthreads();
    bf16x8 af[4], bfr[4];
#pragma unroll
    for (int i = 0; i < 4; ++i)
      af[i] = *(const bf16x8*)((const char*)lds_a + (wr * 64 + i * 16 + lrow) * 64 + lk * 16);
#pragma unroll
    for (int j = 0; j < 4; ++j)
      bfr[j] = *(const bf16x8*)((const char*)lds_b + (wc * 64 + j * 16 + lrow) * 64 + lk * 16);
#pragma unroll
    for (int i = 0; i < 4; ++i)
#pragma unroll
      for (int j = 0; j < 4; ++j)
        acc[i][j] = __builtin_amdgcn_mfma_f32_16x16x32_bf16(af[i], bfr[j], acc[i][j], 0, 0, 0);
    __syncthreads();
  }

#pragma unroll
  for (int i = 0; i < 4; ++i) {
#pragma unroll
    for (int r = 0; r < 4; ++r) {
      const int row = tm + wr * 64 + i * 16 + lk * 4 + r;  // token
      const float gw = gatew[(size_t)row * NE + n];
#pragma unroll
      for (int j = 0; j < 4; ++j) {
        const int col = tn + wc * 64 + j * 16 + lrow;      // h
        float v = acc[i][j][r] + b1[(size_t)n * HH + col];
        v = fmaxf(v, 0.0f) * gw;
        H1s[((size_t)n * B_TOK + row) * HH + col] = f2bf(v);
      }
    }
  }
}

// ---------------- FFN2: part[z][b,o] = sum_{n in half z} H1s[n,b,:] @ W2[n,o,:] ----------------
__global__ __launch_bounds__(256, 2) void moe_ffn2_kernel(
    const unsigned short* __restrict__ H1s,   // [N,B,H]
    const unsigned short* __restrict__ W2bf,  // [N,O,H]
    float* __restrict__ part) {               // [2][B,O]
  const int zp = blockIdx.z;
  const int tm = blockIdx.y * 128;  // token base
  const int tn = blockIdx.x * 128;  // o base
  const int t  = threadIdx.x;
  const int l  = t & 63;
  const int w  = t >> 6;
  const int wr = w >> 1, wc = w & 1;
  const int lrow = l & 15, lk = l >> 4;

  __shared__ __align__(16) unsigned short lds_a[128 * 32];
  __shared__ __align__(16) unsigned short lds_b[128 * 32];

  f32x4 acc[4][4] = {};

  char* la = (char*)lds_a + w * 1024;
  char* lb = (char*)lds_b + w * 1024;
  const int r0 = t >> 2;
  const int cb = (t & 3) * 8;

  for (int n = zp * 4; n < zp * 4 + 4; ++n) {
    const unsigned short* Abase = H1s + ((size_t)n * B_TOK + tm) * HH;
    const unsigned short* Bbase = W2bf + ((size_t)n * OO + tn) * HH;
    for (int kk = 0; kk < HH / 32; ++kk) {
      const unsigned short* Ak = Abase + kk * 32 + cb;
      const unsigned short* Bk = Bbase + kk * 32 + cb;
      gload_lds16(Ak + (size_t)r0 * HH, la);
      gload_lds16(Ak + (size_t)(r0 + 64) * HH, la + 4096);
      gload_lds16(Bk + (size_t)r0 * HH, lb);
      gload_lds16(Bk + (size_t)(r0 + 64) * HH, lb + 4096);
      __syncthreads();
      bf16x8 af[4], bfr[4];
#pragma unroll
      for (int i = 0; i < 4; ++i)
        af[i] = *(const bf16x8*)((const char*)lds_a + (wr * 64 + i * 16 + lrow) * 64 + lk * 16);
#pragma unroll
      for (int j = 0; j < 4; ++j)
        bfr[j] = *(const bf16x8*)((const char*)lds_b + (wc * 64 + j * 16 + lrow) * 64 + lk * 16);
#pragma unroll
      for (int i = 0; i < 4; ++i)
#pragma unroll
        for (int j = 0; j < 4; ++j)
          acc[i][j] = __builtin_amdgcn_mfma_f32_16x16x32_bf16(af[i], bfr[j], acc[i][j], 0, 0, 0);
      __syncthreads();
    }
  }

  float* pout = part + (size_t)zp * B_TOK * OO;
#pragma unroll
  for (int i = 0; i < 4; ++i) {
#pragma unroll
    for (int r = 0; r < 4; ++r) {
      const int row = tm + wr * 64 + i * 16 + lk * 4 + r;  // token
#pragma unroll
      for (int j = 0; j < 4; ++j) {
        const int col = tn + wc * 64 + j * 16 + lrow;      // o
        pout[(size_t)row * OO + col] = acc[i][j][r];
      }
    }
  }
}

// ---------------- finalize: out = part0 + part1 + sum_n w[b,n]*b2[n,o] ----------------
__global__ void moe_finalize_kernel(const float* __restrict__ part,
                                    const float* __restrict__ gatew,
                                    const float* __restrict__ b2,
                                    float* __restrict__ out) {
  const int e4 = blockIdx.x * blockDim.x + threadIdx.x;
  if (e4 >= B_TOK * OO / 4) return;
  const int b  = e4 >> 8;     // 256 float4 per row
  const int o4 = e4 & 255;
  const float4 p0 = ((const float4*)part)[e4];
  const float4 p1 = ((const float4*)(part + (size_t)B_TOK * OO))[e4];
  float sx = p0.x + p1.x, sy = p0.y + p1.y, sz = p0.z + p1.z, sw = p0.w + p1.w;
#pragma unroll
  for (int n = 0; n < NE; ++n) {
    const float gw = gatew[(size_t)b * NE + n];
    const float4 bb = ((const float4*)(b2 + (size_t)n * OO))[o4];
    sx += gw * bb.x; sy += gw * bb.y; sz += gw * bb.z; sw += gw * bb.w;
  }
  float4 r; r.x = sx; r.y = sy; r.z = sz; r.w = sw;
  ((float4*)out)[e4] = r;
}

extern "C" void kernel_launch(void* const* d_in, const int* in_sizes, int n_in,
                              void* d_out, int out_size, void* d_ws, size_t ws_size,
                              hipStream_t stream) {
  const float* x  = (const float*)d_in[0];
  const float* W1 = (const float*)d_in[1];
  const float* b1 = (const float*)d_in[2];
  const float* W2 = (const float*)d_in[3];
  const float* b2 = (const float*)d_in[4];
  const float* Wg = (const float*)d_in[5];
  const float* bg = (const float*)d_in[6];
  float* out = (float*)d_out;

  char* ws = (char*)d_ws;
  unsigned short* xbf   = (unsigned short*)(ws);                       // 8 MB
  unsigned short* W1bf  = (unsigned short*)(ws + (size_t)(8u)  * (1u << 20));  // 64 MB
  unsigned short* W2bf  = (unsigned short*)(ws + (size_t)(72u) * (1u << 20));  // 64 MB
  float*          gatew = (float*)(ws + (size_t)(136u) * (1u << 20));          // 128 KB (pad 2MB)
  unsigned short* H1s   = (unsigned short*)(ws + (size_t)(138u) * (1u << 20)); // 256 MB
  float*          part  = (float*)(ws + (size_t)(394u) * (1u << 20));          // 32 MB
  // total ws use: 426 MB

  moe_cvt_kernel<<<2048, 256, 0, stream>>>(x, xbf, B_TOK * DD / 4);
  moe_cvt_kernel<<<2048, 256, 0, stream>>>(W1, W1bf, NE * HH * DD / 4);
  moe_cvt_kernel<<<2048, 256, 0, stream>>>(W2, W2bf, NE * OO * HH / 4);
  moe_gate_kernel<<<B_TOK, 256, 0, stream>>>(x, Wg, bg, gatew);
  moe_ffn1_kernel<<<dim3(HH / 128, B_TOK / 128, NE), 256, 0, stream>>>(xbf, W1bf, b1, gatew, H1s);
  moe_ffn2_kernel<<<dim3(OO / 128, B_TOK / 128, 2), 256, 0, stream>>>(H1s, W2bf, part);
  moe_finalize_kernel<<<(B_TOK * OO / 4) / 256, 256, 0, stream>>>(part, gatew, b2, out);
}

// Round 3
// 1003.591 us; speedup vs baseline: 1.1999x; 1.1999x over previous
//
#include <hip/hip_runtime.h>
#include <stdint.h>

// MoE: B=4096 tokens, D=1024, H=4096, O=1024, N=8 experts, top-5 Boltzmann gate (T=e).
// R2 (resubmit after infra flake): FFN2 z=4 split (4 blk/CU), launch_bounds(256,4),
// XCD-chunk swizzle on both FFNs. part[4] aliases W1bf (dead after FFN1).

#define B_TOK 4096
#define DD 1024
#define HH 4096
#define OO 1024
#define NE 8
#define NA_K 5

typedef __attribute__((ext_vector_type(8))) __bf16 bf16x8;
typedef __attribute__((ext_vector_type(4))) float f32x4;

__device__ __forceinline__ unsigned short f2bf(float f) {
  unsigned u = __float_as_uint(f);
  u += 0x7FFF + ((u >> 16) & 1);   // round-to-nearest-even
  return (unsigned short)(u >> 16);
}

__device__ __forceinline__ void gload_lds16(const void* g, void* l) {
  __builtin_amdgcn_global_load_lds(
      (const __attribute__((address_space(1))) void*)g,
      (__attribute__((address_space(3))) void*)l, 16, 0, 0);
}

// ---------------- fp32 -> bf16 convert ----------------
__global__ void moe_cvt_kernel(const float* __restrict__ src,
                               unsigned short* __restrict__ dst, int count4) {
  int i = blockIdx.x * blockDim.x + threadIdx.x;
  const int stride = gridDim.x * blockDim.x;
  for (; i < count4; i += stride) {
    const float4 v = ((const float4*)src)[i];
    ushort4 o;
    o.x = f2bf(v.x); o.y = f2bf(v.y); o.z = f2bf(v.z); o.w = f2bf(v.w);
    ((ushort4*)dst)[i] = o;
  }
}

// ---------------- gate: logits -> softmax/T -> top-5 -> renorm weights ----------------
__global__ __launch_bounds__(256) void moe_gate_kernel(
    const float* __restrict__ x, const float* __restrict__ Wg,
    const float* __restrict__ bg, float* __restrict__ gatew) {
  const int b = blockIdx.x;
  const int t = threadIdx.x;
  const float4 xv = ((const float4*)(x + (size_t)b * DD))[t];
  float part[NE];
#pragma unroll
  for (int n = 0; n < NE; ++n) {
    const float4 wv = ((const float4*)(Wg + (size_t)n * DD))[t];
    part[n] = xv.x * wv.x + xv.y * wv.y + xv.z * wv.z + xv.w * wv.w;
  }
#pragma unroll
  for (int n = 0; n < NE; ++n)
#pragma unroll
    for (int off = 32; off > 0; off >>= 1)
      part[n] += __shfl_down(part[n], off);
  __shared__ float red[4][NE];
  const int l = t & 63, w = t >> 6;
  if (l == 0) {
#pragma unroll
    for (int n = 0; n < NE; ++n) red[w][n] = part[n];
  }
  __syncthreads();
  if (t == 0) {
    float lg[NE];
#pragma unroll
    for (int n = 0; n < NE; ++n)
      lg[n] = red[0][n] + red[1][n] + red[2][n] + red[3][n] + bg[n];
    float mx = lg[0];
#pragma unroll
    for (int n = 1; n < NE; ++n) mx = fmaxf(mx, lg[n]);
    const float invT = 0.36787944117144233f;  // 1/e
    float p[NE], s = 0.0f;
#pragma unroll
    for (int n = 0; n < NE; ++n) { p[n] = expf((lg[n] - mx) * invT); s += p[n]; }
#pragma unroll
    for (int n = 0; n < NE; ++n) p[n] /= s;
    bool sel[NE];
#pragma unroll
    for (int n = 0; n < NE; ++n) sel[n] = false;
    float ssum = 0.0f;
    for (int k2 = 0; k2 < NA_K; ++k2) {   // stable argmax: lowest index wins ties (lax.top_k)
      int best = -1; float bv = -1e30f;
      for (int n = 0; n < NE; ++n)
        if (!sel[n] && p[n] > bv) { bv = p[n]; best = n; }
      sel[best] = true; ssum += p[best];
    }
    const float inv = 1.0f / (ssum + 1e-8f);
#pragma unroll
    for (int n = 0; n < NE; ++n)
      gatew[(size_t)b * NE + n] = sel[n] ? p[n] * inv : 0.0f;
  }
}

// ---------------- FFN1: H1s[n,b,h] = relu(x@W1[n]^T + b1[n]) * w[b,n]  (bf16) ----------------
// 1D grid 8192 = 32(tn) x 32(tm) x 8(n), XCD-chunk swizzle: one expert per XCD.
__global__ __launch_bounds__(256, 4) void moe_ffn1_kernel(
    const unsigned short* __restrict__ xbf,   // [B,D]
    const unsigned short* __restrict__ W1bf,  // [N,H,D]
    const float* __restrict__ b1,             // [N,H]
    const float* __restrict__ gatew,          // [B,N]
    unsigned short* __restrict__ H1s) {       // [N,B,H]
  const int nwg = 8192;
  const int lid = (blockIdx.x % 8) * (nwg / 8) + (blockIdx.x / 8);
  const int tn = (lid & 31) * 128;          // h base (inner: shares A-panel)
  const int tm = ((lid >> 5) & 31) * 128;   // token base
  const int n  = lid >> 10;                 // expert
  const int t  = threadIdx.x;
  const int l  = t & 63;
  const int w  = t >> 6;
  const int wr = w >> 1, wc = w & 1;
  const int lrow = l & 15, lk = l >> 4;

  __shared__ __align__(16) unsigned short lds_a[128 * 32];
  __shared__ __align__(16) unsigned short lds_b[128 * 32];

  const unsigned short* Abase = xbf + (size_t)tm * DD;
  const unsigned short* Bbase = W1bf + ((size_t)n * HH + tn) * DD;

  f32x4 acc[4][4] = {};

  char* la = (char*)lds_a + w * 1024;
  char* lb = (char*)lds_b + w * 1024;
  const int r0 = t >> 2;          // tile row for staging
  const int cb = (t & 3) * 8;     // tile col (elems)

  for (int kk = 0; kk < DD / 32; ++kk) {
    const unsigned short* Ak = Abase + kk * 32 + cb;
    const unsigned short* Bk = Bbase + kk * 32 + cb;
    gload_lds16(Ak + (size_t)r0 * DD, la);
    gload_lds16(Ak + (size_t)(r0 + 64) * DD, la + 4096);
    gload_lds16(Bk + (size_t)r0 * DD, lb);
    gload_lds16(Bk + (size_t)(r0 + 64) * DD, lb + 4096);
    __syncthreads();
    bf16x8 af[4], bfr[4];
#pragma unroll
    for (int i = 0; i < 4; ++i)
      af[i] = *(const bf16x8*)((const char*)lds_a + (wr * 64 + i * 16 + lrow) * 64 + lk * 16);
#pragma unroll
    for (int j = 0; j < 4; ++j)
      bfr[j] = *(const bf16x8*)((const char*)lds_b + (wc * 64 + j * 16 + lrow) * 64 + lk * 16);
#pragma unroll
    for (int i = 0; i < 4; ++i)
#pragma unroll
      for (int j = 0; j < 4; ++j)
        acc[i][j] = __builtin_amdgcn_mfma_f32_16x16x32_bf16(af[i], bfr[j], acc[i][j], 0, 0, 0);
    __syncthreads();
  }

#pragma unroll
  for (int i = 0; i < 4; ++i) {
#pragma unroll
    for (int r = 0; r < 4; ++r) {
      const int row = tm + wr * 64 + i * 16 + lk * 4 + r;  // token
      const float gw = gatew[(size_t)row * NE + n];
#pragma unroll
      for (int j = 0; j < 4; ++j) {
        const int col = tn + wc * 64 + j * 16 + lrow;      // h
        float v = acc[i][j][r] + b1[(size_t)n * HH + col];
        v = fmaxf(v, 0.0f) * gw;
        H1s[((size_t)n * B_TOK + row) * HH + col] = f2bf(v);
      }
    }
  }
}

// ---------------- FFN2: part[z][b,o] = sum_{n in 2z..2z+1} H1s[n,b,:] @ W2[n,o,:] ----------------
// 1D grid 1024 = 8(tn) x 32(tm) x 4(z), XCD-chunk swizzle. 4 blocks/CU.
__global__ __launch_bounds__(256, 4) void moe_ffn2_kernel(
    const unsigned short* __restrict__ H1s,   // [N,B,H]
    const unsigned short* __restrict__ W2bf,  // [N,O,H]
    float* __restrict__ part) {               // [4][B,O]
  const int nwg = 1024;
  const int lid = (blockIdx.x % 8) * (nwg / 8) + (blockIdx.x / 8);
  const int tn = (lid & 7) * 128;           // o base (inner: shares A-panel)
  const int tm = ((lid >> 3) & 31) * 128;   // token base
  const int zp = lid >> 8;                  // 0..3 -> experts 2z, 2z+1
  const int t  = threadIdx.x;
  const int l  = t & 63;
  const int w  = t >> 6;
  const int wr = w >> 1, wc = w & 1;
  const int lrow = l & 15, lk = l >> 4;

  __shared__ __align__(16) unsigned short lds_a[128 * 32];
  __shared__ __align__(16) unsigned short lds_b[128 * 32];

  f32x4 acc[4][4] = {};

  char* la = (char*)lds_a + w * 1024;
  char* lb = (char*)lds_b + w * 1024;
  const int r0 = t >> 2;
  const int cb = (t & 3) * 8;

  for (int n = zp * 2; n < zp * 2 + 2; ++n) {
    const unsigned short* Abase = H1s + ((size_t)n * B_TOK + tm) * HH;
    const unsigned short* Bbase = W2bf + ((size_t)n * OO + tn) * HH;
    for (int kk = 0; kk < HH / 32; ++kk) {
      const unsigned short* Ak = Abase + kk * 32 + cb;
      const unsigned short* Bk = Bbase + kk * 32 + cb;
      gload_lds16(Ak + (size_t)r0 * HH, la);
      gload_lds16(Ak + (size_t)(r0 + 64) * HH, la + 4096);
      gload_lds16(Bk + (size_t)r0 * HH, lb);
      gload_lds16(Bk + (size_t)(r0 + 64) * HH, lb + 4096);
      __syncthreads();
      bf16x8 af[4], bfr[4];
#pragma unroll
      for (int i = 0; i < 4; ++i)
        af[i] = *(const bf16x8*)((const char*)lds_a + (wr * 64 + i * 16 + lrow) * 64 + lk * 16);
#pragma unroll
      for (int j = 0; j < 4; ++j)
        bfr[j] = *(const bf16x8*)((const char*)lds_b + (wc * 64 + j * 16 + lrow) * 64 + lk * 16);
#pragma unroll
      for (int i = 0; i < 4; ++i)
#pragma unroll
        for (int j = 0; j < 4; ++j)
          acc[i][j] = __builtin_amdgcn_mfma_f32_16x16x32_bf16(af[i], bfr[j], acc[i][j], 0, 0, 0);
      __syncthreads();
    }
  }

  float* pout = part + (size_t)zp * B_TOK * OO;
#pragma unroll
  for (int i = 0; i < 4; ++i) {
#pragma unroll
    for (int r = 0; r < 4; ++r) {
      const int row = tm + wr * 64 + i * 16 + lk * 4 + r;  // token
#pragma unroll
      for (int j = 0; j < 4; ++j) {
        const int col = tn + wc * 64 + j * 16 + lrow;      // o
        pout[(size_t)row * OO + col] = acc[i][j][r];
      }
    }
  }
}

// ---------------- finalize: out = sum_z part[z] + sum_n w[b,n]*b2[n,o] ----------------
__global__ void moe_finalize_kernel(const float* __restrict__ part,
                                    const float* __restrict__ gatew,
                                    const float* __restrict__ b2,
                                    float* __restrict__ out) {
  const int e4 = blockIdx.x * blockDim.x + threadIdx.x;
  if (e4 >= B_TOK * OO / 4) return;
  const int b  = e4 >> 8;     // 256 float4 per row
  const int o4 = e4 & 255;
  float sx = 0.f, sy = 0.f, sz = 0.f, sw = 0.f;
#pragma unroll
  for (int z = 0; z < 4; ++z) {
    const float4 p = ((const float4*)(part + (size_t)z * B_TOK * OO))[e4];
    sx += p.x; sy += p.y; sz += p.z; sw += p.w;
  }
#pragma unroll
  for (int n = 0; n < NE; ++n) {
    const float gw = gatew[(size_t)b * NE + n];
    const float4 bb = ((const float4*)(b2 + (size_t)n * OO))[o4];
    sx += gw * bb.x; sy += gw * bb.y; sz += gw * bb.z; sw += gw * bb.w;
  }
  float4 r; r.x = sx; r.y = sy; r.z = sz; r.w = sw;
  ((float4*)out)[e4] = r;
}

extern "C" void kernel_launch(void* const* d_in, const int* in_sizes, int n_in,
                              void* d_out, int out_size, void* d_ws, size_t ws_size,
                              hipStream_t stream) {
  const float* x  = (const float*)d_in[0];
  const float* W1 = (const float*)d_in[1];
  const float* b1 = (const float*)d_in[2];
  const float* W2 = (const float*)d_in[3];
  const float* b2 = (const float*)d_in[4];
  const float* Wg = (const float*)d_in[5];
  const float* bg = (const float*)d_in[6];
  float* out = (float*)d_out;

  const size_t MB = 1u << 20;
  char* ws = (char*)d_ws;
  unsigned short* xbf   = (unsigned short*)(ws);                 // [0,8) MB
  float*          gatew = (float*)(ws + 8 * MB);                 // [8,10) MB (128 KB used)
  unsigned short* W2bf  = (unsigned short*)(ws + 10 * MB);       // [10,74) MB
  unsigned short* H1s   = (unsigned short*)(ws + 74 * MB);       // [74,330) MB
  unsigned short* W1bf  = (unsigned short*)(ws + 330 * MB);      // [330,394) MB
  float*          part  = (float*)(ws + 330 * MB);               // [330,394) MB, aliases W1bf (dead after FFN1)

  moe_cvt_kernel<<<2048, 256, 0, stream>>>(x, xbf, B_TOK * DD / 4);
  moe_cvt_kernel<<<2048, 256, 0, stream>>>(W1, W1bf, NE * HH * DD / 4);
  moe_cvt_kernel<<<2048, 256, 0, stream>>>(W2, W2bf, NE * OO * HH / 4);
  moe_gate_kernel<<<B_TOK, 256, 0, stream>>>(x, Wg, bg, gatew);
  moe_ffn1_kernel<<<8192, 256, 0, stream>>>(xbf, W1bf, b1, gatew, H1s);
  moe_ffn2_kernel<<<1024, 256, 0, stream>>>(H1s, W2bf, part);
  moe_finalize_kernel<<<(B_TOK * OO / 4 + 255) / 256, 256, 0, stream>>>(part, gatew, b2, out);
}